// Round 10
// baseline (93.225 us; speedup 1.0000x reference)
//
#include <hip/hip_runtime.h>
#include <hip/hip_bf16.h>
#include <stdint.h>

#define BATCH 2
#define NPTS  2048
#define CIN   64
#define COUT  64
#define NCELL 9

// knorm = 315 / (64*pi*0.1^9)  -- folded into dC at prep time
#define KNORM 1.5666851e9f
#define R2 0.01f

typedef __attribute__((ext_vector_type(8))) __bf16 bf16x8;
typedef __attribute__((ext_vector_type(4))) float  f32x4;

union B8 { uint4 u; bf16x8 v; };

typedef __attribute__((address_space(3))) uint8_t        lds_t;
typedef const __attribute__((address_space(1))) uint8_t  glb_t;

static __device__ __forceinline__ unsigned pk2(float a, float b) {
    union { __hip_bfloat162 h; unsigned u; } cv;
    cv.h = __float22bfloat162_rn(make_float2(a, b));
    return cv.u;
}

// spread 4 bits to even positions (Morton interleave helper)
static __device__ __forceinline__ int mpart(int v) {
    v = (v | (v << 2)) & 0x33;
    v = (v | (v << 1)) & 0x55;
    return v;
}

// ---------------------------------------------------------------------------
// Workspace:
//   posT  float2[B*N]   (SORTED order)   32 KB
//   dC    bf16 [B][C][N] (SORTED j)     512 KB  -- scaled by KNORM
//   WB    bf16 [9][2ks][4ob][64][8]      72 KB  -- GEMM2 B pre-swizzled frags
//   perm  int  [B*N]  sorted->orig       16 KB
//   cbox  float4[B*64]  32-pt chunk bbox  2 KB
//   ibox  float4[B*128] 16-pt tile bbox   4 KB
//   invp  int  [B*N]  orig->sorted       16 KB
//   tmpO  float[B][COUT][N] sorted acc    1 MB  (L2-resident, init = bias)
// ---------------------------------------------------------------------------

// prep stage 1: per-batch Morton counting sort (one block per batch) + WB
// swizzle + tmpO bias-init.
__global__ __launch_bounds__(256) void prep_sort(
    const float* __restrict__ locs, const float* __restrict__ weight,
    const float* __restrict__ bias,
    float2* __restrict__ posT, uint16_t* __restrict__ WB,
    int* __restrict__ perm, int* __restrict__ invp,
    float4* __restrict__ cbox, float4* __restrict__ ibox,
    float* __restrict__ tmpO)
{
    const int tid = threadIdx.x;
    const int g = blockIdx.x;
    if (g < 2) {
        const int b = g;
        __shared__ float2 spos[2048];
        __shared__ float2 ssrt[2048];
        __shared__ short  scll[2048];
        __shared__ int    hist[256];
        __shared__ int    scn[256];
        hist[tid] = 0;
        __syncthreads();
#pragma unroll
        for (int u = 0; u < 8; u++) {
            int idx = u * 256 + tid;
            float x = locs[(b * 2048 + idx) * 3];
            float y = locs[(b * 2048 + idx) * 3 + 1];
            int cx = (int)(x * 16.0f); cx = cx < 0 ? 0 : (cx > 15 ? 15 : cx);
            int cy = (int)(y * 16.0f); cy = cy < 0 ? 0 : (cy > 15 ? 15 : cy);
            spos[idx] = make_float2(x, y);
            scll[idx] = (short)(mpart(cx) | (mpart(cy) << 1));
            atomicAdd(&hist[scll[idx]], 1);
        }
        __syncthreads();
        int v = hist[tid];
        scn[tid] = v;
        __syncthreads();
        for (int ofs = 1; ofs < 256; ofs <<= 1) {
            int t = (tid >= ofs) ? scn[tid - ofs] : 0;
            __syncthreads();
            scn[tid] += t;
            __syncthreads();
        }
        hist[tid] = scn[tid] - v;           // exclusive base, becomes counter
        __syncthreads();
#pragma unroll
        for (int u = 0; u < 8; u++) {
            int idx = u * 256 + tid;
            int c = scll[idx];
            int dst = atomicAdd(&hist[c], 1);
            float2 p = spos[idx];
            ssrt[dst] = p;
            posT[b * 2048 + dst] = p;
            perm[b * 2048 + dst] = idx;
            invp[b * 2048 + idx] = dst;
        }
        __syncthreads();
        if (tid < 64) {                     // 32-pt chunk bboxes
            float xmn = 1e30f, xmx = -1e30f, ymn = 1e30f, ymx = -1e30f;
            for (int u = 0; u < 32; u++) {
                float2 p = ssrt[tid * 32 + u];
                xmn = fminf(xmn, p.x); xmx = fmaxf(xmx, p.x);
                ymn = fminf(ymn, p.y); ymx = fmaxf(ymx, p.y);
            }
            cbox[b * 64 + tid] = make_float4(xmn, xmx, ymn, ymx);
        }
        if (tid < 128) {                    // 16-pt i-tile bboxes
            float xmn = 1e30f, xmx = -1e30f, ymn = 1e30f, ymx = -1e30f;
            for (int u = 0; u < 16; u++) {
                float2 p = ssrt[tid * 16 + u];
                xmn = fminf(xmn, p.x); xmx = fmaxf(xmx, p.x);
                ymn = fminf(ymn, p.y); ymx = fmaxf(ymx, p.y);
            }
            ibox[b * 128 + tid] = make_float4(xmn, xmx, ymn, ymx);
        }
    } else if (g < 2 + NCELL) {
        // WB[cell][ks][ob][lane][jj]: o = ob*16 + (lane&15), c = ks*32 + quad*8 + jj
        int cell = g - 2;
        for (int it = 0; it < 16; it++) {
            int e = it * 256 + tid;
            int ks = e >> 11, ob = (e >> 9) & 3, lane = (e >> 3) & 63, jj = e & 7;
            int o = ob * 16 + (lane & 15);
            int c = ks * 32 + ((lane >> 4) & 3) * 8 + jj;
            union { __hip_bfloat16 h; uint16_t u; } cv;
            cv.h = __float2bfloat16(weight[(o * 64 + c) * 9 + cell]);
            WB[cell * 4096 + e] = cv.u;
        }
    } else {
        // tmpO = bias[o]  (coalesced atomic accumulation target, SORTED order)
        const int gb = g - (2 + NCELL);
#pragma unroll
        for (int r = 0; r < 2; r++) {
            int e4 = (gb * 512 + r * 256 + tid) * 4;
            float bv = bias[(e4 >> 11) & 63];
            *(float4*)(tmpO + e4) = make_float4(bv, bv, bv, bv);
        }
    }
}

// prep stage 2: dC in SORTED j order via perm gather.
__global__ __launch_bounds__(256) void prep_dc(
    const float* __restrict__ locs, const float* __restrict__ data,
    const float* __restrict__ density, const int* __restrict__ perm,
    uint16_t* __restrict__ dC)
{
    int e = blockIdx.x * 256 + threadIdx.x;   // 4 sorted j each
    int j4 = e & 511, bc = e >> 9;
    int b = bc >> 6;
    float vv[4];
#pragma unroll
    for (int u = 0; u < 4; u++) {
        int jo = perm[b * 2048 + j4 * 4 + u];
        float d  = data[bc * 2048 + jo];
        float de = density[b * 2048 + jo];
        float m  = locs[(b * 2048 + jo) * 3 + 2];
        vv[u] = d / (m * de) * KNORM;
    }
    *(uint2*)(dC + bc * 2048 + j4 * 4) = make_uint2(pk2(vv[0], vv[1]), pk2(vv[2], vv[3]));
}

// final: un-permute with COALESCED writes + L2-hot gathered reads (bias
// already folded into tmpO init).
__global__ __launch_bounds__(256) void unperm_kernel(
    const float* __restrict__ tmpO, const int* __restrict__ invp,
    float* __restrict__ out)
{
    int e = blockIdx.x * 256 + threadIdx.x;   // 4 orig i each
    int i4 = e & 511, bo = e >> 9;
    int b = bo >> 6;
    const float* trow = tmpO + bo * 2048;
    const int* ip = invp + b * 2048 + i4 * 4;
    float4 o;
    o.x = trow[ip[0]];
    o.y = trow[ip[1]];
    o.z = trow[ip[2]];
    o.w = trow[ip[3]];
    *(float4*)(out + bo * 2048 + i4 * 4) = o;
}

// ---------------------------------------------------------------------------
// Fused conv over SORTED points, j-split x8, PER-CELL sparsity masks:
// block = 16 sorted-i tile x 256 sorted-j range (8 chunks of 32 j).
// Six per-axis interval masks (ox,oy in {-.05,0,+.05}) give EXACT per-cell
// chunk masks: cell k live iff dx-interval+ox hits (-0.1005,0.1005) AND
// dy likewise (|dx+ox|>=0.1005 => (dx+ox)^2 >= 0.0101 > r2 => w==0).
// Block mask = OR(ax)&OR(ay) (tighter than r7-r9's 0.1505 box); waves skip
// geometry+CELL for chunks where their cells are all dead, and skip a
// cell's GEMM2 entirely when its mask is empty (acc exactly zero).
// Epilogue atomics coalesced into L2-resident tmpO (r9 fix: perm-scatter
// dirtied 64B lines -> 32MB writes, ~510GB/s RMW-bound).
//   [ledger: r6 dense 32 / r9 sparse+coalesced ~20-28 / r7-r8 scatter 42-65.
//    56 VGPR + 48 AGPR caps 4 waves/SIMD; do NOT raise launch_bounds (r4
//    spilled 460MB). Reg-prefetch of B-frags fails: vmcnt in-order (r5).]
// CELLS cost-aware: rank0:{0,2} rank1:{6,8} rank2:{1,3,4} rank3:{5,7},
// heavy rank rotated per block. GEMM2 per-wave via private LDS transpose
// slice; block-reduce + coalesced fp32 atomics into tmpO.
// ---------------------------------------------------------------------------
__global__ __launch_bounds__(256, 4) void conv_kernel(
    const float2* __restrict__ posT, const uint16_t* __restrict__ dC,
    const uint16_t* __restrict__ WB, const float4* __restrict__ cbox,
    const float4* __restrict__ ibox, float* __restrict__ tmpO)
{
    __shared__ uint16_t db[2][2048];          // 2 x 4KB: [c][32j] bf16, unpadded
    __shared__ float    sft[4 * 16 * 68];     // per-wave transpose/reduce slices

    const int tid  = threadIdx.x;
    const int lane = tid & 63;
    const int wid  = tid >> 6;
    const int cl   = lane & 15;
    const int quad = lane >> 4;
    const int bx   = blockIdx.x;
    const int b    = bx >> 10;
    const int i0   = ((bx >> 3) & 127) * 16;
    const int jh   = bx & 7;                  // j-range [jh*256, jh*256+256)
    const int jb0  = jh * 256;

    // heavy rank rotated per block (SIMD issue balance across co-resident blocks)
    const int hw = ((bx >> 8) + bx) & 3;
    const int r  = (wid - hw) & 3;

    // six per-axis interval bit-masks over the 8 chunks (block-uniform)
    const float4 ib = ibox[b * 128 + (i0 >> 4)];
    uint32_t axm = 0, ax0 = 0, axp = 0, aym = 0, ay0 = 0, ayp = 0;
    for (int c = 0; c < 8; c++) {
        float4 cb = cbox[b * 64 + jh * 8 + c];
        float lox = ib.x - cb.y, hix = ib.y - cb.x;   // dx range
        float loy = ib.z - cb.w, hiy = ib.w - cb.z;   // dy range
        uint32_t bit = 1u << c;
        if (lox < 0.1505f && hix > -0.0505f) axm |= bit;   // ox = -0.05
        if (lox < 0.1005f && hix > -0.1005f) ax0 |= bit;   // ox =  0
        if (lox < 0.0505f && hix > -0.1505f) axp |= bit;   // ox = +0.05
        if (loy < 0.1505f && hiy > -0.0505f) aym |= bit;   // oy = -0.05
        if (loy < 0.1005f && hiy > -0.1005f) ay0 |= bit;   // oy =  0
        if (loy < 0.0505f && hiy > -0.1505f) ayp |= bit;   // oy = +0.05
    }
    const uint32_t mask = (axm | ax0 | axp) & (aym | ay0 | ayp);
    if (mask == 0) return;                    // uniform: whole block far away

    // per-cell chunk masks for this wave's cells (rank -> cells, offsets):
    // r0:{k0(-,-),k2(-,+)} r1:{k6(+,-),k8(+,+)} r2:{k1(-,0),k3(0,-),k4(0,0)}
    // r3:{k5(0,+),k7(+,0)}
    uint32_t m0, m1, m2;
    if (r == 0)      { m0 = axm & aym; m1 = axm & ayp; m2 = 0; }
    else if (r == 1) { m0 = axp & aym; m1 = axp & ayp; m2 = 0; }
    else if (r == 2) { m0 = axm & ay0; m1 = ax0 & aym; m2 = ax0 & ay0; }
    else             { m0 = ax0 & ayp; m1 = axp & ay0; m2 = 0; }
    const uint32_t mw = m0 | m1 | m2;

    const float2 pI = posT[b * 2048 + i0 + cl];
    const float2* pbase = posT + b * 2048 + jb0;

    f32x4 acc[3][4];
#pragma unroll
    for (int ci = 0; ci < 3; ci++)
#pragma unroll
        for (int nb = 0; nb < 4; nb++) acc[ci][nb] = (f32x4){0.f, 0.f, 0.f, 0.f};

    // staging: one global_load_lds(16B) per thread per chunk
    const uint16_t* srcbase =
        dC + (b * 64 + wid * 16 + (lane >> 2)) * 2048 + jb0 + (lane & 3) * 8;

#define STAGE(n, buf)                                                         \
    __builtin_amdgcn_global_load_lds((glb_t*)(srcbase + (n) * 32),            \
                                     (lds_t*)(&db[buf][wid * 512]), 16, 0, 0)

#define CELL(CI, CX, CY, CC, HASX, HASY)                                      \
    {                                                                         \
        float w_[8];                                                          \
        _Pragma("unroll")                                                     \
        for (int p = 0; p < 8; p++) {                                         \
            float t = sv[p];                                                  \
            if (HASY) t = fmaf((CY), dyv[p], t);                              \
            if (HASX) t = fmaf((CX), dxv[p], t);                              \
            if ((HASX) || (HASY)) t += (CC);                                  \
            float mt = fmaxf(t, 0.0f);                                        \
            w_[p] = (mt * mt) * mt;                                           \
        }                                                                     \
        B8 af;                                                                \
        af.u = make_uint4(pk2(w_[0], w_[1]), pk2(w_[2], w_[3]),               \
                          pk2(w_[4], w_[5]), pk2(w_[6], w_[7]));              \
        _Pragma("unroll")                                                     \
        for (int nb = 0; nb < 4; nb++)                                        \
            acc[CI][nb] = __builtin_amdgcn_mfma_f32_16x16x32_bf16(            \
                af.v, bf[nb].v, acc[CI][nb], 0, 0, 0);                        \
    }

    {
        int cur = __builtin_ctz(mask);
        uint32_t rem = mask & (mask - 1);
        int bufp = 0;
        STAGE(cur, 0);
        while (cur >= 0) {
            __syncthreads();                  // chunk cur staged (vmcnt drained)
            int nxt = rem ? (int)__builtin_ctz(rem) : -1;
            if (nxt >= 0) { STAGE(nxt, bufp ^ 1); rem &= rem - 1; }

            if ((mw >> cur) & 1) {            // wave-uniform: any of my cells live
                // B-frags: dcoef[j=quad*8..+7][c=nb*16+cl]
                B8 bf[4];
#pragma unroll
                for (int nb = 0; nb < 4; nb++)
                    bf[nb].u = *(const uint4*)&db[bufp][(nb * 16 + cl) * 32 + quad * 8];

                // my 8 pair geometries (pj from L1-hot sorted posT)
                const float4* pp = (const float4*)(pbase + cur * 32 + quad * 8);
                float4 q0 = pp[0], q1 = pp[1], q2 = pp[2], q3 = pp[3];
                float dxv[8], dyv[8], sv[8];
                dxv[0] = pI.x - q0.x; dyv[0] = pI.y - q0.y;
                dxv[1] = pI.x - q0.z; dyv[1] = pI.y - q0.w;
                dxv[2] = pI.x - q1.x; dyv[2] = pI.y - q1.y;
                dxv[3] = pI.x - q1.z; dyv[3] = pI.y - q1.w;
                dxv[4] = pI.x - q2.x; dyv[4] = pI.y - q2.y;
                dxv[5] = pI.x - q2.z; dyv[5] = pI.y - q2.w;
                dxv[6] = pI.x - q3.x; dyv[6] = pI.y - q3.y;
                dxv[7] = pI.x - q3.z; dyv[7] = pI.y - q3.w;
#pragma unroll
                for (int p = 0; p < 8; p++)
                    sv[p] = fmaf(-dyv[p], dyv[p], fmaf(-dxv[p], dxv[p], R2));

                const bool c0 = (m0 >> cur) & 1;
                const bool c1 = (m1 >> cur) & 1;
                const bool c2 = (m2 >> cur) & 1;
                if (r == 0) {            // corners k=0 (-,-), k=2 (-,+)
                    if (c0) CELL(0,  0.1f,  0.1f, -0.005f,  1, 1);
                    if (c1) CELL(1,  0.1f, -0.1f, -0.005f,  1, 1);
                } else if (r == 1) {     // corners k=6 (+,-), k=8 (+,+)
                    if (c0) CELL(0, -0.1f,  0.1f, -0.005f,  1, 1);
                    if (c1) CELL(1, -0.1f, -0.1f, -0.005f,  1, 1);
                } else if (r == 2) {     // edges k=1 (-,0), k=3 (0,-), center k=4
                    if (c0) CELL(0,  0.1f,  0.0f, -0.0025f, 1, 0);
                    if (c1) CELL(1,  0.0f,  0.1f, -0.0025f, 0, 1);
                    if (c2) CELL(2,  0.0f,  0.0f,  0.0f,    0, 0);
                } else {                 // edges k=5 (0,+), k=7 (+,0)
                    if (c0) CELL(0,  0.0f, -0.1f, -0.0025f, 0, 1);
                    if (c1) CELL(1, -0.1f,  0.0f, -0.0025f, 1, 0);
                }
            }

            cur = nxt; bufp ^= 1;
        }
    }

    // cell ids owned by this wave rank (acc index -> absolute cell k)
    const int nc = (r == 2) ? 3 : 2;
    int kcs[3];
    if (r == 0)      { kcs[0] = 0; kcs[1] = 2; kcs[2] = 0; }
    else if (r == 1) { kcs[0] = 6; kcs[1] = 8; kcs[2] = 0; }
    else if (r == 2) { kcs[0] = 1; kcs[1] = 3; kcs[2] = 4; }
    else             { kcs[0] = 5; kcs[1] = 7; kcs[2] = 0; }
    const uint32_t cms[3] = { m0, m1, m2 };

    // ---- GEMM2 per wave: out16x64 partial = sum_{own LIVE cells} field.W --
    float* scr = &sft[wid * (16 * 68)];
    f32x4 acc2[4];
#pragma unroll
    for (int ob = 0; ob < 4; ob++) acc2[ob] = (f32x4){0.f, 0.f, 0.f, 0.f};

#pragma unroll
    for (int ci = 0; ci < 3; ci++) {
        if (ci < nc && cms[ci]) {             // skip cells with zero acc
            // C-frag (row=i=quad*4+rr, col=c=nb*16+cl) -> scr[i][c]
#pragma unroll
            for (int nb = 0; nb < 4; nb++)
#pragma unroll
                for (int rr = 0; rr < 4; rr++)
                    scr[(quad * 4 + rr) * 68 + nb * 16 + cl] = acc[ci][nb][rr];
            // A-frags (m=i=cl, k=c=quad*8+jj) + WB B-frags
            int k = kcs[ci];
#pragma unroll
            for (int ks = 0; ks < 2; ks++) {
                const float* fp = &scr[cl * 68 + ks * 32 + quad * 8];
                float4 lo = *(const float4*)fp;
                float4 hi = *(const float4*)(fp + 4);
                B8 af;
                af.u = make_uint4(pk2(lo.x, lo.y), pk2(lo.z, lo.w),
                                  pk2(hi.x, hi.y), pk2(hi.z, hi.w));
#pragma unroll
                for (int ob = 0; ob < 4; ob++) {
                    B8 wf;
                    wf.u = *(const uint4*)(WB + k * 4096 + (ks * 4 + ob) * 512 + lane * 8);
                    acc2[ob] = __builtin_amdgcn_mfma_f32_16x16x32_bf16(
                        af.v, wf.v, acc2[ob], 0, 0, 0);
                }
            }
        }
    }

    // acc2 C-frag (row=i=quad*4+rr, col=o'=cl; o=ob*16+cl) -> scr[i][o]
#pragma unroll
    for (int ob = 0; ob < 4; ob++)
#pragma unroll
        for (int rr = 0; rr < 4; rr++)
            scr[(quad * 4 + rr) * 68 + ob * 16 + cl] = acc2[ob][rr];
    __syncthreads();

    // reduce 4 wave-slices, COALESCED fp32 atomics into tmpO (sorted order)
    {
        const int i  = tid & 15;
        const int og = tid >> 4;              // 16 groups of 4 o
        float4 s0 = *(const float4*)&sft[0 * 1088 + i * 68 + og * 4];
        float4 s1 = *(const float4*)&sft[1 * 1088 + i * 68 + og * 4];
        float4 s2 = *(const float4*)&sft[2 * 1088 + i * 68 + og * 4];
        float4 s3 = *(const float4*)&sft[3 * 1088 + i * 68 + og * 4];
        float v0 = s0.x + s1.x + s2.x + s3.x;
        float v1 = s0.y + s1.y + s2.y + s3.y;
        float v2 = s0.z + s1.z + s2.z + s3.z;
        float v3 = s0.w + s1.w + s2.w + s3.w;
        float* ob_ = tmpO + (b * 64 + og * 4) * 2048 + i0 + i;
        unsafeAtomicAdd(ob_ + 0 * 2048, v0);
        unsafeAtomicAdd(ob_ + 1 * 2048, v1);
        unsafeAtomicAdd(ob_ + 2 * 2048, v2);
        unsafeAtomicAdd(ob_ + 3 * 2048, v3);
    }
#undef STAGE
#undef CELL
}

extern "C" void kernel_launch(void* const* d_in, const int* in_sizes, int n_in,
                              void* d_out, int out_size, void* d_ws, size_t ws_size,
                              hipStream_t stream)
{
    const float* locs    = (const float*)d_in[0];   // (B, N, 3)
    const float* data    = (const float*)d_in[1];   // (B, CIN, N)
    const float* density = (const float*)d_in[2];   // (B, N)
    const float* weight  = (const float*)d_in[3];   // (COUT, CIN, 9)
    const float* bias    = (const float*)d_in[4];   // (COUT,)
    float* out = (float*)d_out;                     // (B, COUT, N)

    float2*   posT = (float2*)d_ws;                                  // 32768 B
    uint16_t* dC   = (uint16_t*)((char*)d_ws + 32768);               // 524288 B
    uint16_t* WB   = (uint16_t*)((char*)d_ws + 32768 + 524288);      // 73728 B
    int*      perm = (int*)((char*)d_ws + 630784);                   // 16384 B
    float4*   cbox = (float4*)((char*)d_ws + 647168);                // 2048 B
    float4*   ibox = (float4*)((char*)d_ws + 649216);                // 4096 B
    int*      invp = (int*)((char*)d_ws + 653312);                   // 16384 B
    float*    tmpO = (float*)((char*)d_ws + 669696);                 // 1048576 B

    prep_sort<<<2 + NCELL + 128, 256, 0, stream>>>(
        locs, weight, bias, posT, WB, perm, invp, cbox, ibox, tmpO);
    prep_dc<<<256, 256, 0, stream>>>(locs, data, density, perm, dC);
    conv_kernel<<<BATCH * 128 * 8, 256, 0, stream>>>(
        posT, dC, WB, cbox, ibox, tmpO);
    unperm_kernel<<<256, 256, 0, stream>>>(tmpO, invp, out);
}

// Round 11
// 90.021 us; speedup vs baseline: 1.0356x; 1.0356x over previous
//
#include <hip/hip_runtime.h>
#include <hip/hip_bf16.h>
#include <stdint.h>

#define BATCH 2
#define NPTS  2048
#define CIN   64
#define COUT  64
#define NCELL 9

// knorm = 315 / (64*pi*0.1^9)  -- folded into dC at prep time
#define KNORM 1.5666851e9f
#define R2 0.01f

typedef __attribute__((ext_vector_type(8))) __bf16 bf16x8;
typedef __attribute__((ext_vector_type(4))) float  f32x4;

union B8 { uint4 u; bf16x8 v; };

typedef __attribute__((address_space(3))) uint8_t        lds_t;
typedef const __attribute__((address_space(1))) uint8_t  glb_t;

static __device__ __forceinline__ unsigned pk2(float a, float b) {
    union { __hip_bfloat162 h; unsigned u; } cv;
    cv.h = __float22bfloat162_rn(make_float2(a, b));
    return cv.u;
}

// ---------------------------------------------------------------------------
// Workspace:
//   posT  float2[B*N]                    32 KB
//   dC    bf16  [B][C][N]  (c-major)    512 KB   -- scaled by KNORM
//   WB    bf16  [9][2ks][4ob][64][8]     72 KB   -- GEMM2 B pre-swizzled frags
//
// SESSION LEDGER (measured conv_kernel cost, MI355X):
//   r6  staged-LDS, 1 barrier/chunk, cost-aware cells   ~32us  dur 88.96  BEST
//   r1  staged-LDS, uniform cells                       ~33us  dur 90.91
//   r9  sparse sort+bbox skip, coalesced tmpO           ~20-25 + 10-15 overhead
//       (sparse loses at N=2048: prep chain > conv savings; wins only N>~8K)
//   r2  paired staging (2 chunks/barrier)                44us  (longer drain)
//   r3  no staging, direct global B-frags                46us  (load-use stall)
//   r5  register double-buffer prefetch                  65us  (vmcnt in-order
//       drains prefetch at the posT loads + unified-file spill)
//   r4  __launch_bounds__(256,8)                        175us  (460MB scratch)
//   -> occupancy is register-capped at 4 waves/SIMD (56 VGPR + 48 AGPR acc);
//      the structural floor is the per-chunk barrier+vmcnt drain, which at
//      4-way TLP is already mostly hidden; all deeper-pipelining attempts at
//      HIP source level regressed. Remaining dur_us = ~80us harness poison
//      fills at 84% HBM peak (their roofline) + ~9us chain.
// ---------------------------------------------------------------------------

__global__ __launch_bounds__(256) void prep_kernel(
    const float* __restrict__ locs, const float* __restrict__ data,
    const float* __restrict__ density, const float* __restrict__ weight,
    const float* __restrict__ bias,
    float2* __restrict__ posT, uint16_t* __restrict__ dC,
    uint16_t* __restrict__ WB, float* __restrict__ out)
{
    const int tid = threadIdx.x;
    const int g = blockIdx.x;
    if (g < 256) {
        // dC[b][c][j] = bf16( KNORM * data / (invmass * density) )
        int e = g * 256 + tid;             // 4 j each
        int j4 = e & 511, bc = e >> 9;
        int b = bc >> 6;
        float4 dv = *(const float4*)(data + bc * 2048 + j4 * 4);
        float4 de = *(const float4*)(density + b * 2048 + j4 * 4);
        int jb = (b * 2048 + j4 * 4) * 3 + 2;
        float m0 = locs[jb], m1 = locs[jb + 3], m2 = locs[jb + 6], m3 = locs[jb + 9];
        float v0 = dv.x / (m0 * de.x) * KNORM;
        float v1 = dv.y / (m1 * de.y) * KNORM;
        float v2 = dv.z / (m2 * de.z) * KNORM;
        float v3 = dv.w / (m3 * de.w) * KNORM;
        *(uint2*)(dC + bc * 2048 + j4 * 4) = make_uint2(pk2(v0, v1), pk2(v2, v3));
    } else if (g < 272) {
        int jj = (g - 256) * 256 + tid;
        posT[jj] = make_float2(locs[jj * 3], locs[jj * 3 + 1]);
    } else if (g < 272 + NCELL) {
        // WB[cell][ks][ob][lane][jj]: o = ob*16 + (lane&15), c = ks*32 + quad*8 + jj
        int cell = g - 272;
        for (int it = 0; it < 16; it++) {
            int e = it * 256 + tid;
            int ks = e >> 11, ob = (e >> 9) & 3, lane = (e >> 3) & 63, jj = e & 7;
            int o = ob * 16 + (lane & 15);
            int c = ks * 32 + ((lane >> 4) & 3) * 8 + jj;
            union { __hip_bfloat16 h; uint16_t u; } cv;
            cv.h = __float2bfloat16(weight[(o * 64 + c) * 9 + cell]);
            WB[cell * 4096 + e] = cv.u;
        }
    } else {
        // out[b][o][i] = bias[o]  (atomic accumulation target)
        const int gb = g - (272 + NCELL);
#pragma unroll
        for (int r = 0; r < 2; r++) {
            int e4 = (gb * 512 + r * 256 + tid) * 4;
            float bv = bias[(e4 >> 11) & 63];
            *(float4*)(out + e4) = make_float4(bv, bv, bv, bv);
        }
    }
}

// ---------------------------------------------------------------------------
// Fused conv, j-split x4: block = 16-i tile x 512-j range (16 chunks of 32 j).
// STRUCTURE = measured optimum: single-chunk LDS staging via global_load_lds
// (no VGPR cost), ONE barrier per chunk; the vmcnt(0) drain at the barrier is
// mostly covered by the ~450cy compute block at 4-way TLP.
// CELLS = cost-aware split (zero offset components kill fmas):
//   t_k = sv + cx*dx + cy*dy + cc, sv = R2-dx^2-dy^2 shared;
//   rank0:{0,2} rank1:{6,8} rank2:{1,3,4} rank3:{5,7}; heavy rank rotated
//   per block (SIMD issue balance). GEMM2 per-wave on own cells via private
//   LDS transpose slice; block-reduce + fp32 atomics into out.
// ---------------------------------------------------------------------------
__global__ __launch_bounds__(256, 4) void conv_kernel(
    const float2* __restrict__ posT, const uint16_t* __restrict__ dC,
    const uint16_t* __restrict__ WB, float* __restrict__ out)
{
    __shared__ uint16_t db[2][2048];          // 2 x 4KB: [c][32j] bf16, unpadded
    __shared__ float    sft[4 * 16 * 68];     // per-wave transpose/reduce slices

    const int tid  = threadIdx.x;
    const int lane = tid & 63;
    const int wid  = tid >> 6;
    const int cl   = lane & 15;
    const int quad = lane >> 4;
    const int bx   = blockIdx.x;
    const int b    = bx >> 9;
    const int i0   = ((bx >> 2) & 127) * 16;
    const int jh   = bx & 3;                  // j-range [jh*512, jh*512+512)
    const int jb0  = jh * 512;

    // heavy rank rotated per block (SIMD issue balance across co-resident blocks)
    const int hw = ((bx >> 8) + bx) & 3;
    const int r  = (wid - hw) & 3;

    const float2 pI = posT[b * 2048 + i0 + cl];
    const float2* pbase = posT + b * 2048 + jb0;

    f32x4 acc[3][4];
#pragma unroll
    for (int ci = 0; ci < 3; ci++)
#pragma unroll
        for (int nb = 0; nb < 4; nb++) acc[ci][nb] = (f32x4){0.f, 0.f, 0.f, 0.f};

    // staging: one global_load_lds(16B) per thread per chunk
    const uint16_t* srcbase =
        dC + (b * 64 + wid * 16 + (lane >> 2)) * 2048 + jb0 + (lane & 3) * 8;

#define STAGE(n, buf)                                                         \
    __builtin_amdgcn_global_load_lds((glb_t*)(srcbase + (n) * 32),            \
                                     (lds_t*)(&db[buf][wid * 512]), 16, 0, 0)

    // per-cell w + 4 MFMA into acc[CI]. CX/CY/CC are literal constants.
#define CELL(CI, CX, CY, CC, HASX, HASY)                                      \
    {                                                                         \
        float w_[8];                                                          \
        _Pragma("unroll")                                                     \
        for (int p = 0; p < 8; p++) {                                         \
            float t = sv[p];                                                  \
            if (HASY) t = fmaf((CY), dyv[p], t);                              \
            if (HASX) t = fmaf((CX), dxv[p], t);                              \
            if ((HASX) || (HASY)) t += (CC);                                  \
            float mt = fmaxf(t, 0.0f);                                        \
            w_[p] = (mt * mt) * mt;                                           \
        }                                                                     \
        B8 af;                                                                \
        af.u = make_uint4(pk2(w_[0], w_[1]), pk2(w_[2], w_[3]),               \
                          pk2(w_[4], w_[5]), pk2(w_[6], w_[7]));              \
        _Pragma("unroll")                                                     \
        for (int nb = 0; nb < 4; nb++)                                        \
            acc[CI][nb] = __builtin_amdgcn_mfma_f32_16x16x32_bf16(            \
                af.v, bf[nb].v, acc[CI][nb], 0, 0, 0);                        \
    }

    STAGE(0, 0);

    for (int n = 0; n < 16; n++) {
        __syncthreads();                      // chunk n staged (vmcnt drained)
        if (n < 15) STAGE(n + 1, (n + 1) & 1);
        const int buf = n & 1;

        // B-frags: dcoef[j=quad*8..+7][c=nb*16+cl]
        B8 bf[4];
#pragma unroll
        for (int nb = 0; nb < 4; nb++)
            bf[nb].u = *(const uint4*)&db[buf][(nb * 16 + cl) * 32 + quad * 8];

        // my 8 pair geometries (pj from L1-hot posT)
        const float4* pp = (const float4*)(pbase + n * 32 + quad * 8);
        float4 q0 = pp[0], q1 = pp[1], q2 = pp[2], q3 = pp[3];
        float dxv[8], dyv[8], sv[8];
        dxv[0] = pI.x - q0.x; dyv[0] = pI.y - q0.y;
        dxv[1] = pI.x - q0.z; dyv[1] = pI.y - q0.w;
        dxv[2] = pI.x - q1.x; dyv[2] = pI.y - q1.y;
        dxv[3] = pI.x - q1.z; dyv[3] = pI.y - q1.w;
        dxv[4] = pI.x - q2.x; dyv[4] = pI.y - q2.y;
        dxv[5] = pI.x - q2.z; dyv[5] = pI.y - q2.w;
        dxv[6] = pI.x - q3.x; dyv[6] = pI.y - q3.y;
        dxv[7] = pI.x - q3.z; dyv[7] = pI.y - q3.w;
#pragma unroll
        for (int p = 0; p < 8; p++)
            sv[p] = fmaf(-dyv[p], dyv[p], fmaf(-dxv[p], dxv[p], R2));

        if (r == 0) {            // corners k=0 (ox,oy=-,-), k=2 (-,+)
            CELL(0,  0.1f,  0.1f, -0.005f,  1, 1);
            CELL(1,  0.1f, -0.1f, -0.005f,  1, 1);
        } else if (r == 1) {     // corners k=6 (+,-), k=8 (+,+)
            CELL(0, -0.1f,  0.1f, -0.005f,  1, 1);
            CELL(1, -0.1f, -0.1f, -0.005f,  1, 1);
        } else if (r == 2) {     // edges k=1 (-,0), k=3 (0,-), center k=4
            CELL(0,  0.1f,  0.0f, -0.0025f, 1, 0);
            CELL(1,  0.0f,  0.1f, -0.0025f, 0, 1);
            CELL(2,  0.0f,  0.0f,  0.0f,    0, 0);
        } else {                 // edges k=5 (0,+), k=7 (+,0)
            CELL(0,  0.0f, -0.1f, -0.0025f, 0, 1);
            CELL(1, -0.1f,  0.0f, -0.0025f, 1, 0);
        }
    }

    // cell ids owned by this wave rank (acc index -> absolute cell k)
    const int nc = (r == 2) ? 3 : 2;
    int kcs[3];
    if (r == 0)      { kcs[0] = 0; kcs[1] = 2; kcs[2] = 0; }
    else if (r == 1) { kcs[0] = 6; kcs[1] = 8; kcs[2] = 0; }
    else if (r == 2) { kcs[0] = 1; kcs[1] = 3; kcs[2] = 4; }
    else             { kcs[0] = 5; kcs[1] = 7; kcs[2] = 0; }

    // ---- GEMM2 per wave: out16x64 partial = sum_{own cells} field_k . W_k --
    float* scr = &sft[wid * (16 * 68)];
    f32x4 acc2[4];
#pragma unroll
    for (int ob = 0; ob < 4; ob++) acc2[ob] = (f32x4){0.f, 0.f, 0.f, 0.f};

#pragma unroll
    for (int ci = 0; ci < 3; ci++) {
        if (ci < nc) {
            // C-frag (row=i=quad*4+rr, col=c=nb*16+cl) -> scr[i][c]
#pragma unroll
            for (int nb = 0; nb < 4; nb++)
#pragma unroll
                for (int rr = 0; rr < 4; rr++)
                    scr[(quad * 4 + rr) * 68 + nb * 16 + cl] = acc[ci][nb][rr];
            // A-frags (m=i=cl, k=c=quad*8+jj) + WB B-frags
            int k = kcs[ci];
#pragma unroll
            for (int ks = 0; ks < 2; ks++) {
                const float* fp = &scr[cl * 68 + ks * 32 + quad * 8];
                float4 lo = *(const float4*)fp;
                float4 hi = *(const float4*)(fp + 4);
                B8 af;
                af.u = make_uint4(pk2(lo.x, lo.y), pk2(lo.z, lo.w),
                                  pk2(hi.x, hi.y), pk2(hi.z, hi.w));
#pragma unroll
                for (int ob = 0; ob < 4; ob++) {
                    B8 wf;
                    wf.u = *(const uint4*)(WB + k * 4096 + (ks * 4 + ob) * 512 + lane * 8);
                    acc2[ob] = __builtin_amdgcn_mfma_f32_16x16x32_bf16(
                        af.v, wf.v, acc2[ob], 0, 0, 0);
                }
            }
        }
    }

    // acc2 C-frag (row=i=quad*4+rr, col=o'=cl; o=ob*16+cl) -> scr[i][o]
    // (scr slice is wave-private; only the cross-wave reduce needs a barrier)
#pragma unroll
    for (int ob = 0; ob < 4; ob++)
#pragma unroll
        for (int rr = 0; rr < 4; rr++)
            scr[(quad * 4 + rr) * 68 + ob * 16 + cl] = acc2[ob][rr];
    __syncthreads();

    // reduce 4 wave-slices, atomically add to out. thread = (og, i)
    {
        const int i  = tid & 15;
        const int og = tid >> 4;              // 16 groups of 4 o
        float4 s0 = *(const float4*)&sft[0 * 1088 + i * 68 + og * 4];
        float4 s1 = *(const float4*)&sft[1 * 1088 + i * 68 + og * 4];
        float4 s2 = *(const float4*)&sft[2 * 1088 + i * 68 + og * 4];
        float4 s3 = *(const float4*)&sft[3 * 1088 + i * 68 + og * 4];
        float v0 = s0.x + s1.x + s2.x + s3.x;
        float v1 = s0.y + s1.y + s2.y + s3.y;
        float v2 = s0.z + s1.z + s2.z + s3.z;
        float v3 = s0.w + s1.w + s2.w + s3.w;
        float* ob_ = out + (b * 64 + og * 4) * 2048 + i0 + i;
        unsafeAtomicAdd(ob_ + 0 * 2048, v0);
        unsafeAtomicAdd(ob_ + 1 * 2048, v1);
        unsafeAtomicAdd(ob_ + 2 * 2048, v2);
        unsafeAtomicAdd(ob_ + 3 * 2048, v3);
    }
#undef STAGE
#undef CELL
}

extern "C" void kernel_launch(void* const* d_in, const int* in_sizes, int n_in,
                              void* d_out, int out_size, void* d_ws, size_t ws_size,
                              hipStream_t stream)
{
    const float* locs    = (const float*)d_in[0];   // (B, N, 3)
    const float* data    = (const float*)d_in[1];   // (B, CIN, N)
    const float* density = (const float*)d_in[2];   // (B, N)
    const float* weight  = (const float*)d_in[3];   // (COUT, CIN, 9)
    const float* bias    = (const float*)d_in[4];   // (COUT,)
    float* out = (float*)d_out;                     // (B, COUT, N)

    float2*   posT = (float2*)d_ws;                             // 32768 B
    uint16_t* dC   = (uint16_t*)((char*)d_ws + 32768);          // 524288 B
    uint16_t* WB   = (uint16_t*)((char*)d_ws + 32768 + 524288); // 73728 B

    prep_kernel<<<272 + NCELL + 128, 256, 0, stream>>>(
        locs, data, density, weight, bias, posT, dC, WB, out);
    conv_kernel<<<BATCH * 128 * 4, 256, 0, stream>>>(posT, dC, WB, out);
}